// Round 1
// baseline (1153.542 us; speedup 1.0000x reference)
//
#include <hip/hip_runtime.h>

typedef __bf16 bf16x8 __attribute__((ext_vector_type(8)));
typedef float f32x4 __attribute__((ext_vector_type(4)));
typedef float f32x2 __attribute__((ext_vector_type(2)));
typedef int i32x4 __attribute__((ext_vector_type(4)));
typedef int i32x2 __attribute__((ext_vector_type(2)));
typedef int i32x8 __attribute__((ext_vector_type(8)));

#define B_ 2
#define S_ 2048
#define H_ 2048
#define V_ 32000
#define NSEG_ 16
#define R_ 256
#define TM_ 1024
#define MAIN_ROWS 4096          // B*S
#define MROWS 6144              // B*S + B*TM

// W is quantized as Wq = fp8(W * 2^9); the 2^-9 is folded into the MFMA
// B-operand E8M0 block scale (byte 118 = 2^-9). A-operand scale = 127 (2^0).
#define WSCALE 512.0f
#define WSCALE_INV 0.001953125f

__device__ __forceinline__ unsigned short f2bf(float f) {
  union { float f; unsigned u; } v; v.f = f;
  unsigned r = (v.u + 0x7fffu + ((v.u >> 16) & 1u)) >> 16;
  return (unsigned short)r;
}

__device__ __forceinline__ i32x4 pack8(const float* __restrict__ src) {
  float4 v0 = *(const float4*)src;
  float4 v1 = *(const float4*)(src + 4);
  union { unsigned short u[8]; i32x4 v; } o;
  o.u[0] = f2bf(v0.x); o.u[1] = f2bf(v0.y); o.u[2] = f2bf(v0.z); o.u[3] = f2bf(v0.w);
  o.u[4] = f2bf(v1.x); o.u[5] = f2bf(v1.y); o.u[6] = f2bf(v1.z); o.u[7] = f2bf(v1.w);
  return o.v;
}

// ---- fp8 e4m3 helpers (HW cvt if available, manual fallback) ----
__device__ __forceinline__ unsigned e4m3_enc(float f) {
  unsigned u = __float_as_uint(f);
  unsigned s = (u >> 24) & 0x80u;
  float a = fabsf(f);
  unsigned mag;
  if (a >= 0.015625f) {
    unsigned b = __float_as_uint(a);
    b += 0x7FFFFu + ((b >> 20) & 1u);       // RNE at 3-bit mantissa
    int e = (int)(b >> 23) - 120;
    unsigned m = (b >> 20) & 7u;
    if (e > 15) { e = 15; m = 6; }          // clamp to 448
    mag = ((unsigned)e << 3) | m;
  } else {
    mag = (unsigned)__float2int_rn(a * 512.f);  // subnormal grid 2^-9
  }
  return s | mag;
}

__device__ __forceinline__ float e4m3_dec(unsigned b) {
  unsigned e = (b >> 3) & 15u, m = b & 7u;
  float mag = e ? __uint_as_float(((e + 120u) << 23) | (m << 20))
                : (float)m * 0.001953125f;
  return (b & 0x80u) ? -mag : mag;
}

__device__ __forceinline__ int pk_fp8x4(float a, float b, float c, float d) {
#if __has_builtin(__builtin_amdgcn_cvt_pk_fp8_f32)
  int w = __builtin_amdgcn_cvt_pk_fp8_f32(a, b, 0, false);
  w = __builtin_amdgcn_cvt_pk_fp8_f32(c, d, w, true);
  return w;
#else
  return (int)e4m3_enc(a) | ((int)e4m3_enc(b) << 8) |
         ((int)e4m3_enc(c) << 16) | ((int)e4m3_enc(d) << 24);
#endif
}

__device__ __forceinline__ unsigned char fp8_1(float v) {
#if __has_builtin(__builtin_amdgcn_cvt_pk_fp8_f32)
  int w = __builtin_amdgcn_cvt_pk_fp8_f32(v, 0.f, 0, false);
  return (unsigned char)(w & 0xff);
#else
  return (unsigned char)e4m3_enc(v);
#endif
}

__device__ __forceinline__ void fp8x4_dec(int v, float* o) {
#if __has_builtin(__builtin_amdgcn_cvt_pk_f32_fp8)
  f32x2 lo = __builtin_amdgcn_cvt_pk_f32_fp8(v, false);
  f32x2 hi = __builtin_amdgcn_cvt_pk_f32_fp8(v, true);
  o[0] = lo[0]; o[1] = lo[1]; o[2] = hi[0]; o[3] = hi[1];
#else
  o[0] = e4m3_dec(v & 0xff); o[1] = e4m3_dec((v >> 8) & 0xff);
  o[2] = e4m3_dec((v >> 16) & 0xff); o[3] = e4m3_dec((v >> 24) & 0xff);
#endif
}

// ---------------- f32 -> fp8 quantize (16 elems/thread) ----------------
__global__ void quant_fp8_k(const float* __restrict__ in, int* __restrict__ out,
                            float scale, int n16) {
  int i = blockIdx.x * 256 + threadIdx.x;
  if (i >= n16) return;
  const float4* p = (const float4*)in + (size_t)i * 4;
  float4 v0 = p[0], v1 = p[1], v2 = p[2], v3 = p[3];
  i32x4 o;
  o[0] = pk_fp8x4(v0.x * scale, v0.y * scale, v0.z * scale, v0.w * scale);
  o[1] = pk_fp8x4(v1.x * scale, v1.y * scale, v1.z * scale, v1.w * scale);
  o[2] = pk_fp8x4(v2.x * scale, v2.y * scale, v2.z * scale, v2.w * scale);
  o[3] = pk_fp8x4(v3.x * scale, v3.y * scale, v3.z * scale, v3.w * scale);
  *((i32x4*)out + i) = o;
}

// ---------------- adapter stage 1: inter = x @ Bm^T  (bf16 MFMA) ----------------
__global__ __launch_bounds__(256)
void adapter1_k(const float* __restrict__ lhs, const int* __restrict__ starts,
                const float* __restrict__ Bm, unsigned short* __restrict__ interb) {
  const int g = blockIdx.x;
  const int b = g >> 4, seg = g & 15;
  __shared__ __align__(16) unsigned short At[64 * 72];
  __shared__ __align__(16) unsigned short Bt[256 * 72];
  const int tid = threadIdx.x;
  const int wave = tid >> 6, lane = tid & 63;
  const int quad = lane >> 4, l16 = lane & 15;
  const int start = starts[b];

  f32x4 acc[4][4];
  for (int i = 0; i < 4; ++i)
    for (int j = 0; j < 4; ++j)
      acc[i][j] = (f32x4){0.f, 0.f, 0.f, 0.f};

  for (int k0 = 0; k0 < H_; k0 += 64) {
    for (int i = 0; i < 2; ++i) {
      int c = tid + i * 256;
      int row = c >> 3, p = c & 7;
      int t = seg * 64 + row;
      const float* src = lhs + ((size_t)b * S_ + start + t) * H_ + k0 + p * 8;
      *(i32x4*)(&At[row * 72 + p * 8]) = pack8(src);
    }
    for (int i = 0; i < 8; ++i) {
      int c = tid + i * 256;
      int row = c >> 3, p = c & 7;
      const float* src = Bm + ((size_t)seg * R_ + row) * H_ + k0 + p * 8;
      *(i32x4*)(&Bt[row * 72 + p * 8]) = pack8(src);
    }
    __syncthreads();
    for (int kk = 0; kk < 64; kk += 32) {
      bf16x8 af[4], bfr[4];
      for (int rt = 0; rt < 4; ++rt)
        af[rt] = __builtin_bit_cast(bf16x8,
            *(const i32x4*)(&At[(rt * 16 + l16) * 72 + kk + quad * 8]));
      for (int ct = 0; ct < 4; ++ct)
        bfr[ct] = __builtin_bit_cast(bf16x8,
            *(const i32x4*)(&Bt[(wave * 64 + ct * 16 + l16) * 72 + kk + quad * 8]));
      for (int rt = 0; rt < 4; ++rt)
        for (int ct = 0; ct < 4; ++ct)
          acc[rt][ct] = __builtin_amdgcn_mfma_f32_16x16x32_bf16(
              af[rt], bfr[ct], acc[rt][ct], 0, 0, 0);
    }
    __syncthreads();
  }
  for (int rt = 0; rt < 4; ++rt)
    for (int ct = 0; ct < 4; ++ct)
      for (int r = 0; r < 4; ++r) {
        int m = rt * 16 + quad * 4 + r;
        int n = wave * 64 + ct * 16 + l16;
        interb[((size_t)g * 64 + m) * R_ + n] = f2bf(acc[rt][ct][r]);
      }
}

// ---------------- adapter stage 2: trans = inter @ Am^T + bias -> Xq (fp8) ----------------
__global__ __launch_bounds__(256)
void adapter2_k(const unsigned short* __restrict__ interb, const float* __restrict__ Am,
                const float* __restrict__ bias, unsigned char* __restrict__ Xq) {
  const int g = blockIdx.x >> 3;
  const int nt = blockIdx.x & 7;
  const int seg = g & 15;
  __shared__ __align__(16) unsigned short At[64 * 72];
  __shared__ __align__(16) unsigned short Bt[256 * 72];
  const int tid = threadIdx.x;
  const int wave = tid >> 6, lane = tid & 63;
  const int quad = lane >> 4, l16 = lane & 15;

  f32x4 acc[4][4];
  for (int i = 0; i < 4; ++i)
    for (int j = 0; j < 4; ++j)
      acc[i][j] = (f32x4){0.f, 0.f, 0.f, 0.f};

  for (int k0 = 0; k0 < R_; k0 += 64) {
    for (int i = 0; i < 2; ++i) {
      int c = tid + i * 256;
      int row = c >> 3, p = c & 7;
      *(i32x4*)(&At[row * 72 + p * 8]) =
          *(const i32x4*)(interb + ((size_t)g * 64 + row) * R_ + k0 + p * 8);
    }
    for (int i = 0; i < 8; ++i) {
      int c = tid + i * 256;
      int row = c >> 3, p = c & 7;
      const float* src = Am + ((size_t)seg * H_ + nt * 256 + row) * R_ + k0 + p * 8;
      *(i32x4*)(&Bt[row * 72 + p * 8]) = pack8(src);
    }
    __syncthreads();
    for (int kk = 0; kk < 64; kk += 32) {
      bf16x8 af[4], bfr[4];
      for (int rt = 0; rt < 4; ++rt)
        af[rt] = __builtin_bit_cast(bf16x8,
            *(const i32x4*)(&At[(rt * 16 + l16) * 72 + kk + quad * 8]));
      for (int ct = 0; ct < 4; ++ct)
        bfr[ct] = __builtin_bit_cast(bf16x8,
            *(const i32x4*)(&Bt[(wave * 64 + ct * 16 + l16) * 72 + kk + quad * 8]));
      for (int rt = 0; rt < 4; ++rt)
        for (int ct = 0; ct < 4; ++ct)
          acc[rt][ct] = __builtin_amdgcn_mfma_f32_16x16x32_bf16(
              af[rt], bfr[ct], acc[rt][ct], 0, 0, 0);
    }
    __syncthreads();
  }
  for (int rt = 0; rt < 4; ++rt)
    for (int ct = 0; ct < 4; ++ct)
      for (int r = 0; r < 4; ++r) {
        int m = rt * 16 + quad * 4 + r;
        int h = nt * 256 + wave * 64 + ct * 16 + l16;
        float v = acc[rt][ct][r] + bias[seg * H_ + h];
        Xq[((size_t)(MAIN_ROWS + g * 64 + m)) * H_ + h] = fp8_1(v);
      }
}

// ---------------- fused CE GEMM (MX-fp8, K=128) — 256x256 tile, 8-wave 8-phase ----------------
// rowsum[m] += sum_n exp(X[m]·W[n]).  Structure: T2 chunk-XOR swizzle +
// T3/T4 8-phase counted-vmcnt double-buffer + T5 setprio.
#define BM 256
#define BN 256
#define BKB 128    // K-tile: 128 fp8 bytes per row
#define NKT (H_ / BKB)   // 16

// stage one 128-row half-tile of A (X rows) for K-tile kt: 2 loads/thread
#define STAGE_A(kt, h) { \
  _Pragma("unroll") \
  for (int j = 0; j < 2; ++j) \
    __builtin_amdgcn_global_load_lds( \
        (const __attribute__((address_space(1))) void*)(ag + (size_t)((h) * 128 + j * 64) * H_ + (size_t)(kt) * BKB), \
        (__attribute__((address_space(3))) void*)(&Abuf[(kt) & 1][((h) * 128 + j * 64 + wave * 8) * BKB]), 16, 0, 0); }

#define STAGE_B(kt, h) { \
  _Pragma("unroll") \
  for (int j = 0; j < 2; ++j) \
    __builtin_amdgcn_global_load_lds( \
        (const __attribute__((address_space(1))) void*)(bg + (size_t)((h) * 128 + j * 64) * H_ + (size_t)(kt) * BKB), \
        (__attribute__((address_space(3))) void*)(&Bbuf[(kt) & 1][((h) * 128 + j * 64 + wave * 8) * BKB]), 16, 0, 0); }

// read A register quadrant (4 frags of 32B) from half hrt of this wave's 128 rows
#define READ_A(bufi, hrt) { \
  _Pragma("unroll") \
  for (int rt = 0; rt < 4; ++rt) { \
    const unsigned char* base_ = &Abuf[bufi][(wm * 128 + (hrt) * 64 + rt * 16 + l16) * BKB]; \
    i32x4 lo_ = *(const i32x4*)(base_ + cp0 * 16); \
    i32x4 hi_ = *(const i32x4*)(base_ + (cp0 ^ 1) * 16); \
    i32x8 t_; \
    t_[0] = lo_[0]; t_[1] = lo_[1]; t_[2] = lo_[2]; t_[3] = lo_[3]; \
    t_[4] = hi_[0]; t_[5] = hi_[1]; t_[6] = hi_[2]; t_[7] = hi_[3]; \
    af[rt] = t_; } }

// read B register pair (2 frags) for column-quadrant qc of this wave's 64 cols
#define READ_B(bufi, qc) { \
  _Pragma("unroll") \
  for (int ct = 0; ct < 2; ++ct) { \
    const unsigned char* base_ = &Bbuf[bufi][(wn * 64 + (qc) * 32 + ct * 16 + l16) * BKB]; \
    i32x4 lo_ = *(const i32x4*)(base_ + cp0 * 16); \
    i32x4 hi_ = *(const i32x4*)(base_ + (cp0 ^ 1) * 16); \
    i32x8 t_; \
    t_[0] = lo_[0]; t_[1] = lo_[1]; t_[2] = lo_[2]; t_[3] = lo_[3]; \
    t_[4] = hi_[0]; t_[5] = hi_[1]; t_[6] = hi_[2]; t_[7] = hi_[3]; \
    bf[(qc) * 2 + ct] = t_; } }

#define MFMA_Q(rbase, cbase) { \
  _Pragma("unroll") \
  for (int rt = 0; rt < 4; ++rt) \
    _Pragma("unroll") \
    for (int ct = 0; ct < 2; ++ct) \
      acc[(rbase) + rt][(cbase) + ct] = __builtin_amdgcn_mfma_scale_f32_16x16x128_f8f6f4( \
          af[rt], bf[(cbase) + ct], acc[(rbase) + rt][(cbase) + ct], \
          0 /*A=fp8*/, 0 /*B=fp8*/, 0, 127 /*A scale 2^0*/, 0, 118 /*B scale 2^-9*/); }

__global__ __launch_bounds__(512, 2)
void ce_gemm_k(const unsigned char* __restrict__ X, const unsigned char* __restrict__ Wq,
               const int* __restrict__ starts, float* __restrict__ rowsum) {
  const int m0 = blockIdx.x * BM;
  const int n0 = blockIdx.y * BN;
  if (m0 < MAIN_ROWS) {
    int b = m0 >> 11;
    if (m0 + BM - 1 < starts[b] - 1) return;   // fully-masked main-row panel
  }
  __shared__ __align__(16) unsigned char Abuf[2][BM * BKB];   // 2 x 32 KiB
  __shared__ __align__(16) unsigned char Bbuf[2][BN * BKB];   // 2 x 32 KiB
  const int tid = threadIdx.x;
  const int wave = tid >> 6, lane = tid & 63;
  const int quad = lane >> 4, l16 = lane & 15;
  const int wm = wave >> 2, wn = wave & 3;      // 2 x 4 wave grid, wave tile 128x64

  // staging: lane covers row (wave*8 + rsub), dest chunk (lane&7); source chunk
  // pre-swizzled so LDS[row][c] = global[row][c ^ (row&7)]
  const int rsub = lane >> 3;
  const int clog = (lane & 7) ^ rsub;
  const unsigned char* ag = X  + (size_t)(m0 + wave * 8 + rsub) * H_ + clog * 16;
  const unsigned char* bg = Wq + (size_t)(n0 + wave * 8 + rsub) * H_ + clog * 16;

  // fragment read: logical chunk 2q lives at physical (2q)^(row&7); row&7 == l16&7
  const int cp0 = (2 * quad) ^ (l16 & 7);

  f32x4 acc[8][4];
  #pragma unroll
  for (int i = 0; i < 8; ++i)
    #pragma unroll
    for (int j = 0; j < 4; ++j)
      acc[i][j] = (f32x4){0.f, 0.f, 0.f, 0.f};

  i32x8 af[4], bf[4];

  // ---- prologue: stage kt0 fully + kt1's B halves (12 loads/thread) ----
  STAGE_B(0, 0); STAGE_B(0, 1);
  STAGE_A(0, 0); STAGE_A(0, 1);
  STAGE_B(1, 0); STAGE_B(1, 1);
  asm volatile("s_waitcnt vmcnt(4)" ::: "memory");   // kt0 complete; kt1's B in flight
  __builtin_amdgcn_s_barrier();

  for (int kt = 0; kt < NKT; ++kt) {
    const int bufi = kt & 1;
    // ---- P0: A half0 + B cols 0-31; stage A0(kt+1) ----
    READ_A(bufi, 0);
    READ_B(bufi, 0);
    if (kt + 1 < NKT) STAGE_A(kt + 1, 0);
    __builtin_amdgcn_s_barrier();
    asm volatile("s_waitcnt lgkmcnt(0)" ::: "memory");
    __builtin_amdgcn_s_setprio(1);
    MFMA_Q(0, 0);
    __builtin_amdgcn_s_setprio(0);
    __builtin_amdgcn_s_barrier();
    // ---- P1: B cols 32-63; stage A1(kt+1) ----
    READ_B(bufi, 1);
    if (kt + 1 < NKT) STAGE_A(kt + 1, 1);
    __builtin_amdgcn_s_barrier();
    asm volatile("s_waitcnt lgkmcnt(0)" ::: "memory");
    __builtin_amdgcn_s_setprio(1);
    MFMA_Q(0, 2);
    __builtin_amdgcn_s_setprio(0);
    __builtin_amdgcn_s_barrier();
    // ---- P2: A half1; stage B0(kt+2) (B buf reads finished at end of P1) ----
    READ_A(bufi, 1);
    if (kt + 2 < NKT) STAGE_B(kt + 2, 0);
    __builtin_amdgcn_s_barrier();
    asm volatile("s_waitcnt lgkmcnt(0)" ::: "memory");
    __builtin_amdgcn_s_setprio(1);
    MFMA_Q(4, 0);
    __builtin_amdgcn_s_setprio(0);
    __builtin_amdgcn_s_barrier();
    // ---- P3: no ds-reads; stage B1(kt+2); counted vmcnt before tile boundary ----
    if (kt + 2 < NKT) STAGE_B(kt + 2, 1);
    __builtin_amdgcn_s_barrier();
    __builtin_amdgcn_s_setprio(1);
    MFMA_Q(4, 2);
    __builtin_amdgcn_s_setprio(0);
    if (kt < NKT - 2)
      asm volatile("s_waitcnt vmcnt(4)" ::: "memory");   // kt+1's A landed; kt+2's B in flight
    else
      asm volatile("s_waitcnt vmcnt(0)" ::: "memory");   // tail: no B stages issued this tile
    __builtin_amdgcn_s_barrier();
  }

  // ---- epilogue: exp + row-sum reduce ----
  #pragma unroll
  for (int rt = 0; rt < 8; ++rt) {
    float s[4] = {0.f, 0.f, 0.f, 0.f};
    #pragma unroll
    for (int ct = 0; ct < 4; ++ct)
      #pragma unroll
      for (int r = 0; r < 4; ++r)
        s[r] += __expf(acc[rt][ct][r]);
    #pragma unroll
    for (int m = 1; m < 16; m <<= 1)
      #pragma unroll
      for (int r = 0; r < 4; ++r)
        s[r] += __shfl_xor(s[r], m, 64);
    if (l16 == 0) {
      #pragma unroll
      for (int r = 0; r < 4; ++r) {
        int grow = m0 + wm * 128 + rt * 16 + quad * 4 + r;
        atomicAdd(&rowsum[grow], s[r]);
      }
    }
  }
}

// ---------------- target logit per token row (fp8 dequant dot) ----------------
__global__ void tlogit_k(const unsigned char* __restrict__ Xq,
                         const unsigned char* __restrict__ Wq,
                         const int* __restrict__ input_ids,
                         const int* __restrict__ mlabels,
                         float* __restrict__ tlog) {
  int i = blockIdx.x;
  int label;
  if (i < MAIN_ROWS) {
    int b = i >> 11, s = i & 2047;
    label = (s < S_ - 1) ? input_ids[b * S_ + s + 1] : 0;
  } else {
    int j = i - MAIN_ROWS;
    int b = j >> 10, t = j & 1023;
    label = mlabels[b * TM_ + t];
  }
  const unsigned char* x = Xq + (size_t)i * H_;
  const unsigned char* w = Wq + (size_t)label * H_;
  int tid = threadIdx.x;
  i32x2 xv = *(const i32x2*)(x + tid * 8);
  i32x2 wv = *(const i32x2*)(w + tid * 8);
  float acc = 0.f;
  for (int q = 0; q < 2; ++q) {
    float xf[4], wf[4];
    fp8x4_dec(xv[q], xf);
    fp8x4_dec(wv[q], wf);
    acc += xf[0] * wf[0] + xf[1] * wf[1] + xf[2] * wf[2] + xf[3] * wf[3];
  }
  for (int m = 1; m < 64; m <<= 1) acc += __shfl_xor(acc, m, 64);
  __shared__ float red[4];
  if ((tid & 63) == 0) red[tid >> 6] = acc;
  __syncthreads();
  if (tid == 0) tlog[i] = (red[0] + red[1] + red[2] + red[3]) * WSCALE_INV;
}

// ---------------- final masked means ----------------
__global__ void finalize_k(const float* __restrict__ rowsum, const float* __restrict__ tlog,
                           const int* __restrict__ attn, const int* __restrict__ starts,
                           const int* __restrict__ ends, const int* __restrict__ mmask,
                           float* __restrict__ out) {
  int tid = threadIdx.x;
  __shared__ int tmp[8];
  __shared__ float red[24];
  int s0 = 0, s1 = 0;
  for (int s = tid; s < S_; s += 256) { s0 += attn[s]; s1 += attn[S_ + s]; }
  for (int m = 1; m < 64; m <<= 1) { s0 += __shfl_xor(s0, m, 64); s1 += __shfl_xor(s1, m, 64); }
  if ((tid & 63) == 0) { tmp[(tid >> 6) * 2] = s0; tmp[(tid >> 6) * 2 + 1] = s1; }
  __syncthreads();
  int rl[2];
  rl[0] = tmp[0] + tmp[2] + tmp[4] + tmp[6];
  rl[1] = tmp[1] + tmp[3] + tmp[5] + tmp[7];

  float st_s = 0.f, st_c = 0.f, fa_s = 0.f, fa_c = 0.f, m_s = 0.f, m_c = 0.f;
  for (int i = tid; i < MAIN_ROWS; i += 256) {
    int b = i >> 11, s = i & 2047;
    if (s < S_ - 1) {
      bool stm = (s >= starts[b] - 1) && (s <= ends[b] - 1);
      bool fam = (s >= ends[b]) && (s < rl[b] - 1);
      if (stm || fam) {
        float nll = logf(rowsum[i]) - tlog[i];
        if (stm) { st_s += nll; st_c += 1.f; }
        if (fam) { fa_s += nll; fa_c += 1.f; }
      }
    }
  }
  for (int i = tid; i < B_ * TM_; i += 256) {
    int row = MAIN_ROWS + i;
    float nll = logf(rowsum[row]) - tlog[row];
    float m = (float)mmask[i];
    m_s += nll * m; m_c += m;
  }
  float vals[6] = {st_s, st_c, fa_s, fa_c, m_s, m_c};
  for (int m = 1; m < 64; m <<= 1)
    for (int q = 0; q < 6; ++q) vals[q] += __shfl_xor(vals[q], m, 64);
  if ((tid & 63) == 0)
    for (int q = 0; q < 6; ++q) red[(tid >> 6) * 6 + q] = vals[q];
  __syncthreads();
  if (tid == 0) {
    float stS = red[0] + red[6] + red[12] + red[18];
    float stC = red[1] + red[7] + red[13] + red[19];
    float faS = red[2] + red[8] + red[14] + red[20];
    float faC = red[3] + red[9] + red[15] + red[21];
    float mS  = red[4] + red[10] + red[16] + red[22];
    float mC  = red[5] + red[11] + red[17] + red[23];
    float st = stS / fmaxf(stC, 1.f);
    float fa = faS / fmaxf(faC, 1.f);
    float ml = mS / fmaxf(mC, 1.f);
    out[0] = 0.5f * ml + 0.5f * st + 0.4f * fa;
    out[1] = ml;
    out[2] = st;
    out[3] = fa;
  }
}

extern "C" void kernel_launch(void* const* d_in, const int* in_sizes, int n_in,
                              void* d_out, int out_size, void* d_ws, size_t ws_size,
                              hipStream_t stream) {
  (void)in_sizes; (void)n_in; (void)out_size; (void)ws_size;
  const float* lhs      = (const float*)d_in[0];
  const int* input_ids  = (const int*)d_in[1];
  const int* attn       = (const int*)d_in[2];
  const int* starts     = (const int*)d_in[3];
  const int* ends       = (const int*)d_in[4];
  const int* mlabels    = (const int*)d_in[5];
  const int* mmask      = (const int*)d_in[6];
  const float* Am       = (const float*)d_in[8];
  const float* Bm       = (const float*)d_in[9];
  const float* bias     = (const float*)d_in[10];
  const float* Wf       = (const float*)d_in[11];
  float* out = (float*)d_out;

  char* ws = (char*)d_ws;
  unsigned char* Wq     = (unsigned char*)ws;                   // 65,536,000 B
  unsigned char* Xq     = (unsigned char*)(ws + 65536000);      // 12,582,912 B
  unsigned short* interb= (unsigned short*)(ws + 78118912);     //  1,048,576 B
  float* rowsum         = (float*)(ws + 79167488);              //     24,576 B
  float* tlog           = (float*)(ws + 79192064);              //     24,576 B

  hipMemsetAsync(rowsum, 0, MROWS * sizeof(float), stream);
  quant_fp8_k<<<(V_ * H_ / 16 + 255) / 256, 256, 0, stream>>>(Wf, (int*)Wq, WSCALE, V_ * H_ / 16);
  quant_fp8_k<<<(MAIN_ROWS * H_ / 16 + 255) / 256, 256, 0, stream>>>(lhs, (int*)Xq, 1.0f, MAIN_ROWS * H_ / 16);
  adapter1_k<<<B_ * NSEG_, 256, 0, stream>>>(lhs, starts, Bm, interb);
  adapter2_k<<<B_ * NSEG_ * 8, 256, 0, stream>>>(interb, Am, bias, Xq);
  ce_gemm_k<<<dim3(MROWS / BM, V_ / BN), 512, 0, stream>>>(Xq, Wq, starts, rowsum);
  tlogit_k<<<MROWS, 256, 0, stream>>>(Xq, Wq, input_ids, mlabels, tlog);
  finalize_k<<<1, 256, 0, stream>>>(rowsum, tlog, attn, starts, ends, mmask, out);
}